// Round 10
// baseline (346.324 us; speedup 1.0000x reference)
//
#include <hip/hip_runtime.h>
#include <hip/hip_bf16.h>

typedef __attribute__((ext_vector_type(8))) short bf16x8;
typedef __attribute__((ext_vector_type(4))) float f32x4;

static __device__ __forceinline__ unsigned short f2bf(float f){
  __hip_bfloat16 h = __float2bfloat16(f);
  return *reinterpret_cast<unsigned short*>(&h);
}
static __device__ __forceinline__ float bf2f(unsigned short u){
  unsigned int x = ((unsigned int)u) << 16;
  return *reinterpret_cast<float*>(&x);
}
static __device__ __forceinline__ void gload16(const void* g, void* l){
  __builtin_amdgcn_global_load_lds((__attribute__((address_space(1))) void*)g,
                                   (__attribute__((address_space(3))) void*)l, 16, 0, 0);
}
static __device__ __forceinline__ f32x4 mfma16(bf16x8 a, bf16x8 b, f32x4 c){
  return __builtin_amdgcn_mfma_f32_16x16x32_bf16(a, b, c, 0, 0, 0);
}

// ---------------- merged f32 -> bf16 convert ----------------
struct CvtArgs { const float* drug; const float* protein; const float* w[8]; };
__global__ __launch_bounds__(256) void k_cvt_all(CvtArgs a,
                                                 unsigned short* __restrict__ Xd,
                                                 unsigned short* __restrict__ Xp,
                                                 unsigned short* __restrict__ Wb){
  for (int i = blockIdx.x*256 + threadIdx.x; i < 5767168; i += 1048576){
    float4 v; ushort4* dst;
    if (i < 1048576){
      v = reinterpret_cast<const float4*>(a.drug)[i];
      dst = reinterpret_cast<ushort4*>(Xd) + i;
    } else if (i < 5242880){
      const int j = i - 1048576;
      v = reinterpret_cast<const float4*>(a.protein)[j];
      dst = reinterpret_cast<ushort4*>(Xp) + j;
    } else {
      const int j = i - 5242880;
      v = reinterpret_cast<const float4*>(a.w[j>>16])[j & 65535];
      dst = reinterpret_cast<ushort4*>(Wb) + j;
    }
    ushort4 o;
    o.x = f2bf(v.x); o.y = f2bf(v.y); o.z = f2bf(v.z); o.w = f2bf(v.w);
    *dst = o;
  }
}

// ---------------- 128x128 BT projection GEMM, K=512, BK=64, LDS-staged epilogue ----------------
template<int SIDE>
__device__ __forceinline__ void proj_side(int id,
    const unsigned short* __restrict__ A, const unsigned short* __restrict__ W3,
    const float* __restrict__ b0, const float* __restrict__ b1, const float* __restrict__ b2,
    unsigned short* __restrict__ o01, unsigned short* __restrict__ oV,
    const float* __restrict__ alphap, unsigned short* S){
  constexpr int LSH = SIDE ? 10 : 8;
  constexpr int MPX = SIDE ? 32 : 8;
  const int xcd = id & 7, j = id >> 3;
  const int m0 = (xcd*MPX + j/12) * 128;
  const int n0 = (j % 12) * 128;
  const int t = threadIdx.x, l = t&63, w = t>>6;
  const int wm = w>>1, wn = w&1;
  f32x4 acc[4][4] = {};
  const char* Ab = (const char*)A + (size_t)m0*1024;
  const char* Wp = (const char*)W3 + (size_t)n0*1024;
  char* AsB = (char*)S;
  char* BsB = (char*)S + 16384;
  const int grow = t>>3;
  const int gcolb = ((t&7) ^ (grow&7))*16;

  for (int kt=0; kt<8; ++kt){
    __syncthreads();
    const int kb = kt*128;
    for (int i=0;i<4;++i){
      gload16(Ab + (size_t)(i*32 + grow)*1024 + kb + gcolb, AsB + i*4096 + w*1024);
      gload16(Wp + (size_t)(i*32 + grow)*1024 + kb + gcolb, BsB + i*4096 + w*1024);
    }
    __syncthreads();
    bf16x8 a[4][2], b[4][2];
    for (int i=0;i<4;++i){
      const int ra = wm*64 + i*16 + (l&15);
      const int rb = wn*64 + i*16 + (l&15);
      for (int ks=0;ks<2;++ks){
        const int cb = ks*64 + (l>>4)*16;
        a[i][ks] = *(const bf16x8*)(AsB + ra*128 + (cb ^ ((ra&7)<<4)));
        b[i][ks] = *(const bf16x8*)(BsB + rb*128 + (cb ^ ((rb&7)<<4)));
      }
    }
    __builtin_amdgcn_s_setprio(1);
    for (int i=0;i<4;++i)
      for (int jj=0;jj<4;++jj)
        for (int ks=0;ks<2;++ks)
          acc[i][jj] = mfma16(a[i][ks], b[jj][ks], acc[i][jj]);
    __builtin_amdgcn_s_setprio(0);
  }

  __syncthreads();
  const float al = alphap[0];
  const float sg = 1.f/(1.f + __expf(-al));
  const int Lseq = 1 << LSH;
  const int g = n0 >> 9, h0 = (n0 & 511) >> 6;
  const size_t bb = (size_t)(m0 >> LSH);
  const int pos0 = m0 & (Lseq-1);

  for (int i=0;i<4;++i){
    for (int jj=0;jj<4;++jj){
      const int nloc = wn*64 + jj*16 + (l&15);
      const float bv = (g==0 ? b0 : (g==1 ? b1 : b2))[(n0 + nloc) & 511];
      for (int r=0;r<4;++r){
        const int mloc = wm*64 + i*16 + (l>>4)*4 + r;
        float v = acc[i][jj][r] + bv;
        if (g < 2){
          if (SIDE==0) v *= (g==0 ? sg : (1.f-sg)) * 0.125f;
          S[ mloc*128 + ((((nloc*2) ^ ((mloc&15)<<4))) >> 1) ] = f2bf(v);
        } else {
          S[ nloc*128 + ((((mloc*2) ^ ((nloc&15)<<4))) >> 1) ] = f2bf(v);
        }
      }
    }
  }
  __syncthreads();

  if (g < 2){
    for (int it=0; it<8; ++it){
      const int idx = it*256 + t;
      const int hs = idx>>10, pos = (idx>>3)&127, cc = idx&7;
      const int4 val = *(const int4*)((const char*)S + pos*256 + ((hs*128 + cc*16) ^ ((pos&15)<<4)));
      const int h = h0 + hs;
      char* gp = (char*)o01 + ((bb*8+h)*Lseq + pos0 + pos)*256
                 + ((g*128 + cc*16) ^ ((pos&15)<<4));
      *(int4*)gp = val;
    }
  } else {
    for (int it=0; it<8; ++it){
      const int idx = it*256 + t;
      const int hs = idx>>10, dd = (idx>>4)&63, ch = idx&15;
      const int sw = (ch*16) ^ ((dd&15)<<4);
      const int4 val = *(const int4*)((const char*)S + (hs*64+dd)*256 + sw);
      const int h = h0 + hs;
      if (SIDE==1){
        char* gp = (char*)oV + ((bb*8+h)*64 + dd)*2048 + pos0*2 + sw;
        *(int4*)gp = val;
      } else {
        char* gp = (char*)oV + ((bb*8+h)*64 + dd)*512 + pos0*2 + ch*16;
        *(int4*)gp = val;
      }
    }
  }
}

__global__ __launch_bounds__(256) void k_proj_all(
    const unsigned short* __restrict__ Xd, const unsigned short* __restrict__ Xp,
    const unsigned short* __restrict__ Wb,
    const float* __restrict__ bqd, const float* __restrict__ bkd, const float* __restrict__ bvd,
    const float* __restrict__ bkp, const float* __restrict__ bqp, const float* __restrict__ bvp,
    unsigned short* __restrict__ Dm, unsigned short* __restrict__ Pm,
    unsigned short* __restrict__ Vpt, unsigned short* __restrict__ Vdt,
    const float* __restrict__ alphap){
  __shared__ unsigned short S[16384];
  if (blockIdx.x < 3072)
    proj_side<1>(blockIdx.x, Xp, Wb + 3*262144, bkp, bqp, bvp, Pm, Vpt, alphap, S);
  else
    proj_side<0>(blockIdx.x - 3072, Xd, Wb + 0*262144, bqd, bkd, bvd, Dm, Vdt, alphap, S);
}

// ---------------- output projection body (N=512, K=512, BK=64, f32 nt out) ----------------
template<int MPX>
__device__ __forceinline__ void oproj_side(int id,
    const unsigned short* __restrict__ A, const unsigned short* __restrict__ W,
    const float* __restrict__ bias, float* __restrict__ out, char* AsB, char* BsB){
  const int xcd = id & 7, j = id >> 3;
  const int m0 = (xcd*MPX + j/4) * 128;
  const int n0 = (j & 3) * 128;
  const int t = threadIdx.x, l = t&63, w = t>>6;
  const int wm = w>>1, wn = w&1;
  f32x4 acc[4][4] = {};
  const char* Ab = (const char*)A + (size_t)m0*1024;
  const char* Wp = (const char*)W + (size_t)n0*1024;
  const int grow = t>>3;
  const int gcolb = ((t&7) ^ (grow&7))*16;

  for (int kt=0; kt<8; ++kt){
    __syncthreads();
    const int kb = kt*128;
    for (int i=0;i<4;++i){
      gload16(Ab + (size_t)(i*32 + grow)*1024 + kb + gcolb, AsB + i*4096 + w*1024);
      gload16(Wp + (size_t)(i*32 + grow)*1024 + kb + gcolb, BsB + i*4096 + w*1024);
    }
    __syncthreads();
    bf16x8 a[4][2], b[4][2];
    for (int i=0;i<4;++i){
      const int ra = wm*64 + i*16 + (l&15);
      const int rb = wn*64 + i*16 + (l&15);
      for (int ks=0;ks<2;++ks){
        const int cb = ks*64 + (l>>4)*16;
        a[i][ks] = *(const bf16x8*)(AsB + ra*128 + (cb ^ ((ra&7)<<4)));
        b[i][ks] = *(const bf16x8*)(BsB + rb*128 + (cb ^ ((rb&7)<<4)));
      }
    }
    __builtin_amdgcn_s_setprio(1);
    for (int i=0;i<4;++i)
      for (int jj=0;jj<4;++jj)
        for (int ks=0;ks<2;++ks)
          acc[i][jj] = mfma16(a[i][ks], b[jj][ks], acc[i][jj]);
    __builtin_amdgcn_s_setprio(0);
  }
  for (int i=0;i<4;++i)
    for (int jj=0;jj<4;++jj){
      const int nn = n0 + wn*64 + jj*16 + (l&15);
      const float bv = bias[nn];
      for (int r=0;r<4;++r){
        const int mm = m0 + wm*64 + i*16 + (l>>4)*4 + r;
        __builtin_nontemporal_store(acc[i][jj][r] + bv, &out[ (size_t)mm*512 + nn ]);
      }
    }
}

__global__ __launch_bounds__(256) void k_oproj_p(
    const unsigned short* __restrict__ Cp, const unsigned short* __restrict__ Wb,
    const float* __restrict__ bop, float* __restrict__ outp){
  __shared__ unsigned short As[128*64];
  __shared__ unsigned short Bs[128*64];
  oproj_side<32>(blockIdx.x, Cp, Wb + 7*262144, bop, outp, (char*)As, (char*)Bs);
}

// ---------------- fused QK^T + exp + rowsum + spill + ctx_d ----------------
__global__ __launch_bounds__(256) void k_attn_d(const unsigned short* __restrict__ Dm,
                                                const unsigned short* __restrict__ Pm,
                                                const unsigned short* __restrict__ Vpt,
                                                unsigned short* __restrict__ expS,
                                                float* __restrict__ rinv,
                                                unsigned short* __restrict__ Cd){
  __shared__ unsigned short Ds[128*128];
  __shared__ unsigned short Ps[128*128];
  __shared__ unsigned short Vs[64*128];
  const int id = blockIdx.x, xcd = id & 7, j = id >> 3;
  const int bh = xcd*32 + (j>>1), qt = j&1;
  const int b = bh>>3, h = bh&7;
  const int t = threadIdx.x, l = t&63, w = t>>6;
  char* DsB=(char*)Ds; char* PsB=(char*)Ps; char* VsB=(char*)Vs;
  const char* dsrc = (const char*)Dm + ((size_t)bh*256 + qt*128)*256;
  const char* psrc = (const char*)Pm + (size_t)bh*1024*256;
  const char* vsrc = (const char*)Vpt + (size_t)bh*64*2048;
  char* egbase = (char*)expS + ((size_t)bh*256 + qt*128)*2048;
  const int lofs = w*1024;

  for (int i=0;i<8;++i)
    gload16(dsrc + i*4096 + lofs + l*16, DsB + i*4096 + lofs);

  float rs[2][4] = {};
  f32x4 cacc[2][4] = {};
  for (int pt=0; pt<8; ++pt){
    __syncthreads();
    for (int i=0;i<8;++i)
      gload16(psrc + pt*32768 + i*4096 + lofs + l*16, PsB + i*4096 + lofs);
    for (int i=0;i<4;++i){
      const int ib = i*4096 + lofs + l*16;
      gload16(vsrc + (size_t)(ib>>8)*2048 + pt*256 + (ib&255), VsB + i*4096 + lofs);
    }
    __syncthreads();
    f32x4 acc[2][8] = {};
    for (int kt=0;kt<4;++kt){
      bf16x8 a[2];
      for (int fm=0;fm<2;++fm){
        const int row = w*32 + fm*16 + (l&15);
        const int byteo = (kt*64 + (l>>4)*16) ^ ((row&15)<<4);
        a[fm] = *(const bf16x8*)(DsB + row*256 + byteo);
      }
      __builtin_amdgcn_s_setprio(1);
      for (int fn=0;fn<8;++fn){
        const int row = fn*16 + (l&15);
        const int byteo = (kt*64 + (l>>4)*16) ^ ((row&15)<<4);
        bf16x8 bq = *(const bf16x8*)(PsB + row*256 + byteo);
        acc[0][fn] = mfma16(a[0], bq, acc[0][fn]);
        acc[1][fn] = mfma16(a[1], bq, acc[1][fn]);
      }
      __builtin_amdgcn_s_setprio(0);
    }
    __syncthreads();
    for (int fm=0;fm<2;++fm)
      for (int fn=0;fn<8;++fn)
        for (int r=0;r<4;++r){
          float e = __expf(acc[fm][fn][r]);
          rs[fm][r] += e;
          const int q = w*32 + fm*16 + (l>>4)*4 + r;
          const int p = fn*16 + (l&15);
          *(unsigned short*)(PsB + q*256 + ((p*2) ^ ((q&15)<<4))) = f2bf(e);
        }
    __syncthreads();
    for (int i=0;i<4;++i){
      const int idx = i*256 + t;
      const int row = idx>>3, colb = (idx&7)*32;
      int4 v0 = *(const int4*)(PsB + row*256 + colb);
      int4 v1 = *(const int4*)(PsB + row*256 + colb + 16);
      char* gp = egbase + (size_t)row*2048 + pt*256 + colb;
      *(int4*)gp = v0;
      *(int4*)(gp+16) = v1;
    }
    for (int kt=0;kt<4;++kt){
      bf16x8 pa[2], vb[4];
      for (int fm=0;fm<2;++fm){
        const int row = w*32 + fm*16 + (l&15);
        const int byteo = (kt*64 + (l>>4)*16) ^ ((row&15)<<4);
        pa[fm] = *(const bf16x8*)(PsB + row*256 + byteo);
      }
      for (int fn=0;fn<4;++fn){
        const int row = fn*16 + (l&15);
        const int byteo = (kt*64 + (l>>4)*16) ^ ((row&15)<<4);
        vb[fn] = *(const bf16x8*)(VsB + row*256 + byteo);
      }
      __builtin_amdgcn_s_setprio(1);
      for (int fm=0;fm<2;++fm)
        for (int fn=0;fn<4;++fn)
          cacc[fm][fn] = mfma16(pa[fm], vb[fn], cacc[fm][fn]);
      __builtin_amdgcn_s_setprio(0);
    }
  }
  for (int m=1;m<16;m<<=1)
    for (int fm=0;fm<2;++fm)
      for (int r=0;r<4;++r)
        rs[fm][r] += __shfl_xor(rs[fm][r], m, 64);
  float riv[2][4];
  for (int fm=0;fm<2;++fm)
    for (int r=0;r<4;++r)
      riv[fm][r] = 1.f/rs[fm][r];
  if ((l&15)==0){
    for (int fm=0;fm<2;++fm)
      for (int r=0;r<4;++r){
        const int row = w*32 + fm*16 + (l>>4)*4 + r;
        rinv[ (size_t)bh*256 + qt*128 + row ] = riv[fm][r];
      }
  }
  for (int fm=0;fm<2;++fm)
    for (int fn=0;fn<4;++fn)
      for (int r=0;r<4;++r){
        const int row = w*32 + fm*16 + (l>>4)*4 + r;
        const float v = cacc[fm][fn][r] * riv[fm][r];
        const int col = fn*16 + (l&15);
        Cd[ ((size_t)b*256 + qt*128 + row)*512 + h*64 + col ] = f2bf(v);
      }
}

// ---------------- ctx_p body (+ fused normalized-attn write) ----------------
__device__ __forceinline__ void ctxp_body(int id,
    const unsigned short* __restrict__ expS, const unsigned short* __restrict__ Vdt,
    const float* __restrict__ rinv, unsigned short* __restrict__ Cp,
    float* __restrict__ attn, char* SM){
  unsigned short* As = (unsigned short*)SM;            // 128*40*2 = 10240 B
  unsigned short* Bs = (unsigned short*)(SM + 10240);  // 64*40*2  =  5120 B
  float* ri = (float*)(SM + 15360);                    // 256*4    =  1024 B
  const int xcd = id & 7, j = id >> 3;
  const int bh = xcd*32 + (j>>3), mt = j&7;
  const int b = bh>>3, h = bh&7;
  const int t = threadIdx.x, l = t&63, w = t>>6;
  ri[t] = rinv[ (size_t)bh*256 + t ];
  const char* ebase = (const char*)expS + (size_t)bh*256*2048;
  const unsigned short* vbase = Vdt + (size_t)bh*16384;
  f32x4 acc[2][4] = {};
  for (int kt=0; kt<8; ++kt){
    __syncthreads();
    for (int i=0;i<4;++i){
      const int idx = i*256 + t;
      const int ql = idx>>5, p4 = idx&31;
      const int qg = kt*32 + ql;
      ushort4 v = *(const ushort4*)(ebase + (size_t)qg*2048 + ((mt*256 + p4*8) ^ ((qg&15)<<4)));
      As[(p4*4+0)*40 + ql] = v.x;
      As[(p4*4+1)*40 + ql] = v.y;
      As[(p4*4+2)*40 + ql] = v.z;
      As[(p4*4+3)*40 + ql] = v.w;
      const float rv = ri[qg];
      f32x4 o;
      o[0] = bf2f(v.x) * rv; o[1] = bf2f(v.y) * rv;
      o[2] = bf2f(v.z) * rv; o[3] = bf2f(v.w) * rv;
      float* dst = attn + ((size_t)bh*256 + qg)*1024 + mt*128 + p4*4;
      __builtin_nontemporal_store(o, (f32x4*)dst);
    }
    for (int i=0;i<2;++i){
      const int idx = i*256 + t;
      const int row = idx>>3, c4 = idx&7;
      ushort4 vv = *(const ushort4*)(vbase + (size_t)row*256 + kt*32 + c4*4);
      const float* rp = &ri[kt*32 + c4*4];
      Bs[row*40 + c4*4+0] = f2bf(bf2f(vv.x) * rp[0]);
      Bs[row*40 + c4*4+1] = f2bf(bf2f(vv.y) * rp[1]);
      Bs[row*40 + c4*4+2] = f2bf(bf2f(vv.z) * rp[2]);
      Bs[row*40 + c4*4+3] = f2bf(bf2f(vv.w) * rp[3]);
    }
    __syncthreads();
    bf16x8 a[2], bb[4];
    for (int fm=0;fm<2;++fm)
      a[fm] = *(const bf16x8*)(As + (w*32 + fm*16 + (l&15))*40 + (l>>4)*8);
    for (int fn=0;fn<4;++fn)
      bb[fn] = *(const bf16x8*)(Bs + (fn*16 + (l&15))*40 + (l>>4)*8);
    for (int fm=0;fm<2;++fm)
      for (int fn=0;fn<4;++fn)
        acc[fm][fn] = mfma16(a[fm], bb[fn], acc[fm][fn]);
  }
  for (int fm=0;fm<2;++fm)
    for (int fn=0;fn<4;++fn)
      for (int r=0;r<4;++r){
        const int row = mt*128 + w*32 + fm*16 + (l>>4)*4 + r;
        const int col = fn*16 + (l&15);
        Cp[ ((size_t)b*1024 + row)*512 + h*64 + col ] = f2bf(acc[fm][fn][r]);
      }
}

// ---------------- merged: oproj_d (ids 0..255) + ctxp_n (ids 256..2303) ----------------
// Independent consumers of attn_d's outputs; Cd lives in the (not-yet-written) outp
// region of d_out, so oproj_d's reads don't conflict with ctxp_n's attn writes.
__global__ __launch_bounds__(256) void k_cx_od(
    const unsigned short* __restrict__ expS, const unsigned short* __restrict__ Vdt,
    const float* __restrict__ rinv, unsigned short* __restrict__ Cp,
    float* __restrict__ attn,
    const unsigned short* __restrict__ Cd, const unsigned short* __restrict__ Wb,
    const float* __restrict__ bod, float* __restrict__ outd){
  __shared__ char SM[32768];
  if (blockIdx.x < 256)
    oproj_side<8>(blockIdx.x, Cd, Wb + 6*262144, bod, outd, SM, SM + 16384);
  else
    ctxp_body(blockIdx.x - 256, expS, Vdt, rinv, Cp, attn, SM);
}

extern "C" void kernel_launch(void* const* d_in, const int* in_sizes, int n_in,
                              void* d_out, int out_size, void* d_ws, size_t ws_size,
                              hipStream_t stream){
  const float* drug    = (const float*)d_in[0];
  const float* protein = (const float*)d_in[1];
  const float* Wqd=(const float*)d_in[2];  const float* bqd=(const float*)d_in[3];
  const float* Wkp=(const float*)d_in[4];  const float* bkp=(const float*)d_in[5];
  const float* Wvp=(const float*)d_in[6];  const float* bvp=(const float*)d_in[7];
  const float* Wqp=(const float*)d_in[8];  const float* bqp=(const float*)d_in[9];
  const float* Wkd=(const float*)d_in[10]; const float* bkd=(const float*)d_in[11];
  const float* Wvd=(const float*)d_in[12]; const float* bvd=(const float*)d_in[13];
  const float* alpha=(const float*)d_in[14];
  const float* Wod=(const float*)d_in[15]; const float* bod=(const float*)d_in[16];
  const float* Wop=(const float*)d_in[17]; const float* bop=(const float*)d_in[18];

  char* ws = (char*)d_ws;
  unsigned short* expS = (unsigned short*)(ws + 0);          // [bh][256][1024] bf16, p-swizzled
  unsigned short* Xd   = (unsigned short*)(ws + 0);          // dead after proj
  unsigned short* Xp   = (unsigned short*)(ws + 8388608);    // dead after proj
  unsigned short* Wb   = (unsigned short*)(ws + 134217728);  // 8 x 512x512 bf16
  unsigned short* Dm   = (unsigned short*)(ws + 138412032);  // dead after attn_d
  unsigned short* Pm   = (unsigned short*)(ws + 155189248);  // dead after attn_d
  unsigned short* Cp   = (unsigned short*)(ws + 155189248);  // overlay, written post-attn_d
  unsigned short* Vpt  = (unsigned short*)(ws + 222298112);  // [bh][64][1024] swizzled
  unsigned short* Vdt  = (unsigned short*)(ws + 255852544);  // [bh][64][256] linear
  float*          rinv = (float*)         (ws + 264241152);  // [bh*256]

  float* attn = (float*)d_out;
  float* outd = (float*)d_out + 67108864;
  float* outp = (float*)d_out + 71303168;
  // Cd in the outp region (64 MB, written only by the final oproj_p):
  // attn_d writes it, k_cx_od's oproj_d blocks read it concurrently with the
  // ctxp blocks' attn writes (disjoint), oproj_p overwrites it last.
  unsigned short* Cd = (unsigned short*)outp;

  CvtArgs ca;
  ca.drug = drug; ca.protein = protein;
  ca.w[0]=Wqd; ca.w[1]=Wkd; ca.w[2]=Wvd; ca.w[3]=Wkp; ca.w[4]=Wqp; ca.w[5]=Wvp; ca.w[6]=Wod; ca.w[7]=Wop;
  k_cvt_all<<<4096, 256, 0, stream>>>(ca, Xd, Xp, Wb);

  k_proj_all<<<3840, 256, 0, stream>>>(Xd, Xp, Wb, bqd, bkd, bvd, bkp, bqp, bvp,
                                       Dm, Pm, Vpt, Vdt, alpha);

  // fused QK + exp + spill + ctx_d
  k_attn_d<<<512, 256, 0, stream>>>(Dm, Pm, Vpt, expS, rinv, Cd);

  // merged: drug output projection + (ctx_p + normalized f32 attn write)
  k_cx_od<<<2304, 256, 0, stream>>>(expS, Vdt, rinv, Cp, attn, Cd, Wb, bod, outd);

  // protein output projection (overwrites Cd region)
  k_oproj_p<<<1024, 256, 0, stream>>>(Cp, Wb, bop, outp);
}

// Round 11
// 332.973 us; speedup vs baseline: 1.0401x; 1.0401x over previous
//
#include <hip/hip_runtime.h>
#include <hip/hip_bf16.h>

typedef __attribute__((ext_vector_type(8))) short bf16x8;
typedef __attribute__((ext_vector_type(4))) float f32x4;

static __device__ __forceinline__ unsigned short f2bf(float f){
  __hip_bfloat16 h = __float2bfloat16(f);
  return *reinterpret_cast<unsigned short*>(&h);
}
static __device__ __forceinline__ float bf2f(unsigned short u){
  unsigned int x = ((unsigned int)u) << 16;
  return *reinterpret_cast<float*>(&x);
}
static __device__ __forceinline__ void gload16(const void* g, void* l){
  __builtin_amdgcn_global_load_lds((__attribute__((address_space(1))) void*)g,
                                   (__attribute__((address_space(3))) void*)l, 16, 0, 0);
}
static __device__ __forceinline__ f32x4 mfma16(bf16x8 a, bf16x8 b, f32x4 c){
  return __builtin_amdgcn_mfma_f32_16x16x32_bf16(a, b, c, 0, 0, 0);
}

// ---------------- merged f32 -> bf16 convert ----------------
struct CvtArgs { const float* drug; const float* protein; const float* w[8]; };
__global__ __launch_bounds__(256) void k_cvt_all(CvtArgs a,
                                                 unsigned short* __restrict__ Xd,
                                                 unsigned short* __restrict__ Xp,
                                                 unsigned short* __restrict__ Wb){
  for (int i = blockIdx.x*256 + threadIdx.x; i < 5767168; i += 1048576){
    float4 v; ushort4* dst;
    if (i < 1048576){
      v = reinterpret_cast<const float4*>(a.drug)[i];
      dst = reinterpret_cast<ushort4*>(Xd) + i;
    } else if (i < 5242880){
      const int j = i - 1048576;
      v = reinterpret_cast<const float4*>(a.protein)[j];
      dst = reinterpret_cast<ushort4*>(Xp) + j;
    } else {
      const int j = i - 5242880;
      v = reinterpret_cast<const float4*>(a.w[j>>16])[j & 65535];
      dst = reinterpret_cast<ushort4*>(Wb) + j;
    }
    ushort4 o;
    o.x = f2bf(v.x); o.y = f2bf(v.y); o.z = f2bf(v.z); o.w = f2bf(v.w);
    *dst = o;
  }
}

// ---------------- 128x128 BT projection GEMM, K=512, BK=64, LDS-staged epilogue ----------------
template<int SIDE>
__device__ __forceinline__ void proj_side(int id,
    const unsigned short* __restrict__ A, const unsigned short* __restrict__ W3,
    const float* __restrict__ b0, const float* __restrict__ b1, const float* __restrict__ b2,
    unsigned short* __restrict__ o01, unsigned short* __restrict__ oV,
    const float* __restrict__ alphap, unsigned short* S){
  constexpr int LSH = SIDE ? 10 : 8;
  constexpr int MPX = SIDE ? 32 : 8;
  const int xcd = id & 7, j = id >> 3;
  const int m0 = (xcd*MPX + j/12) * 128;
  const int n0 = (j % 12) * 128;
  const int t = threadIdx.x, l = t&63, w = t>>6;
  const int wm = w>>1, wn = w&1;
  f32x4 acc[4][4] = {};
  const char* Ab = (const char*)A + (size_t)m0*1024;
  const char* Wp = (const char*)W3 + (size_t)n0*1024;
  char* AsB = (char*)S;
  char* BsB = (char*)S + 16384;
  const int grow = t>>3;
  const int gcolb = ((t&7) ^ (grow&7))*16;

  for (int kt=0; kt<8; ++kt){
    __syncthreads();
    const int kb = kt*128;
    for (int i=0;i<4;++i){
      gload16(Ab + (size_t)(i*32 + grow)*1024 + kb + gcolb, AsB + i*4096 + w*1024);
      gload16(Wp + (size_t)(i*32 + grow)*1024 + kb + gcolb, BsB + i*4096 + w*1024);
    }
    __syncthreads();
    bf16x8 a[4][2], b[4][2];
    for (int i=0;i<4;++i){
      const int ra = wm*64 + i*16 + (l&15);
      const int rb = wn*64 + i*16 + (l&15);
      for (int ks=0;ks<2;++ks){
        const int cb = ks*64 + (l>>4)*16;
        a[i][ks] = *(const bf16x8*)(AsB + ra*128 + (cb ^ ((ra&7)<<4)));
        b[i][ks] = *(const bf16x8*)(BsB + rb*128 + (cb ^ ((rb&7)<<4)));
      }
    }
    __builtin_amdgcn_s_setprio(1);
    for (int i=0;i<4;++i)
      for (int jj=0;jj<4;++jj)
        for (int ks=0;ks<2;++ks)
          acc[i][jj] = mfma16(a[i][ks], b[jj][ks], acc[i][jj]);
    __builtin_amdgcn_s_setprio(0);
  }

  __syncthreads();
  const float al = alphap[0];
  const float sg = 1.f/(1.f + __expf(-al));
  const int Lseq = 1 << LSH;
  const int g = n0 >> 9, h0 = (n0 & 511) >> 6;
  const size_t bb = (size_t)(m0 >> LSH);
  const int pos0 = m0 & (Lseq-1);

  for (int i=0;i<4;++i){
    for (int jj=0;jj<4;++jj){
      const int nloc = wn*64 + jj*16 + (l&15);
      const float bv = (g==0 ? b0 : (g==1 ? b1 : b2))[(n0 + nloc) & 511];
      for (int r=0;r<4;++r){
        const int mloc = wm*64 + i*16 + (l>>4)*4 + r;
        float v = acc[i][jj][r] + bv;
        if (g < 2){
          if (SIDE==0) v *= (g==0 ? sg : (1.f-sg)) * 0.125f;
          S[ mloc*128 + ((((nloc*2) ^ ((mloc&15)<<4))) >> 1) ] = f2bf(v);
        } else {
          S[ nloc*128 + ((((mloc*2) ^ ((nloc&15)<<4))) >> 1) ] = f2bf(v);
        }
      }
    }
  }
  __syncthreads();

  if (g < 2){
    for (int it=0; it<8; ++it){
      const int idx = it*256 + t;
      const int hs = idx>>10, pos = (idx>>3)&127, cc = idx&7;
      const int4 val = *(const int4*)((const char*)S + pos*256 + ((hs*128 + cc*16) ^ ((pos&15)<<4)));
      const int h = h0 + hs;
      char* gp = (char*)o01 + ((bb*8+h)*Lseq + pos0 + pos)*256
                 + ((g*128 + cc*16) ^ ((pos&15)<<4));
      *(int4*)gp = val;
    }
  } else {
    for (int it=0; it<8; ++it){
      const int idx = it*256 + t;
      const int hs = idx>>10, dd = (idx>>4)&63, ch = idx&15;
      const int sw = (ch*16) ^ ((dd&15)<<4);
      const int4 val = *(const int4*)((const char*)S + (hs*64+dd)*256 + sw);
      const int h = h0 + hs;
      if (SIDE==1){
        char* gp = (char*)oV + ((bb*8+h)*64 + dd)*2048 + pos0*2 + sw;
        *(int4*)gp = val;
      } else {
        char* gp = (char*)oV + ((bb*8+h)*64 + dd)*512 + pos0*2 + ch*16;
        *(int4*)gp = val;
      }
    }
  }
}

__global__ __launch_bounds__(256) void k_proj_all(
    const unsigned short* __restrict__ Xd, const unsigned short* __restrict__ Xp,
    const unsigned short* __restrict__ Wb,
    const float* __restrict__ bqd, const float* __restrict__ bkd, const float* __restrict__ bvd,
    const float* __restrict__ bkp, const float* __restrict__ bqp, const float* __restrict__ bvp,
    unsigned short* __restrict__ Dm, unsigned short* __restrict__ Pm,
    unsigned short* __restrict__ Vpt, unsigned short* __restrict__ Vdt,
    const float* __restrict__ alphap){
  __shared__ unsigned short S[16384];
  if (blockIdx.x < 3072)
    proj_side<1>(blockIdx.x, Xp, Wb + 3*262144, bkp, bqp, bvp, Pm, Vpt, alphap, S);
  else
    proj_side<0>(blockIdx.x - 3072, Xd, Wb + 0*262144, bqd, bkd, bvd, Dm, Vdt, alphap, S);
}

// ---------------- output projection (N=512, K=512, BK=64, f32 nt out) ----------------
template<int MPX>
__device__ __forceinline__ void oproj_side(int id,
    const unsigned short* __restrict__ A, const unsigned short* __restrict__ W,
    const float* __restrict__ bias, float* __restrict__ out, char* AsB, char* BsB){
  const int xcd = id & 7, j = id >> 3;
  const int m0 = (xcd*MPX + j/4) * 128;
  const int n0 = (j & 3) * 128;
  const int t = threadIdx.x, l = t&63, w = t>>6;
  const int wm = w>>1, wn = w&1;
  f32x4 acc[4][4] = {};
  const char* Ab = (const char*)A + (size_t)m0*1024;
  const char* Wp = (const char*)W + (size_t)n0*1024;
  const int grow = t>>3;
  const int gcolb = ((t&7) ^ (grow&7))*16;

  for (int kt=0; kt<8; ++kt){
    __syncthreads();
    const int kb = kt*128;
    for (int i=0;i<4;++i){
      gload16(Ab + (size_t)(i*32 + grow)*1024 + kb + gcolb, AsB + i*4096 + w*1024);
      gload16(Wp + (size_t)(i*32 + grow)*1024 + kb + gcolb, BsB + i*4096 + w*1024);
    }
    __syncthreads();
    bf16x8 a[4][2], b[4][2];
    for (int i=0;i<4;++i){
      const int ra = wm*64 + i*16 + (l&15);
      const int rb = wn*64 + i*16 + (l&15);
      for (int ks=0;ks<2;++ks){
        const int cb = ks*64 + (l>>4)*16;
        a[i][ks] = *(const bf16x8*)(AsB + ra*128 + (cb ^ ((ra&7)<<4)));
        b[i][ks] = *(const bf16x8*)(BsB + rb*128 + (cb ^ ((rb&7)<<4)));
      }
    }
    __builtin_amdgcn_s_setprio(1);
    for (int i=0;i<4;++i)
      for (int jj=0;jj<4;++jj)
        for (int ks=0;ks<2;++ks)
          acc[i][jj] = mfma16(a[i][ks], b[jj][ks], acc[i][jj]);
    __builtin_amdgcn_s_setprio(0);
  }
  for (int i=0;i<4;++i)
    for (int jj=0;jj<4;++jj){
      const int nn = n0 + wn*64 + jj*16 + (l&15);
      const float bv = bias[nn];
      for (int r=0;r<4;++r){
        const int mm = m0 + wm*64 + i*16 + (l>>4)*4 + r;
        __builtin_nontemporal_store(acc[i][jj][r] + bv, &out[ (size_t)mm*512 + nn ]);
      }
    }
}

__global__ __launch_bounds__(256) void k_oproj_d(
    const unsigned short* __restrict__ Cd, const unsigned short* __restrict__ Wb,
    const float* __restrict__ bod, float* __restrict__ outd){
  __shared__ unsigned short As[128*64];
  __shared__ unsigned short Bs[128*64];
  oproj_side<8>(blockIdx.x, Cd, Wb + 6*262144, bod, outd, (char*)As, (char*)Bs);
}
__global__ __launch_bounds__(256) void k_oproj_p(
    const unsigned short* __restrict__ Cp, const unsigned short* __restrict__ Wb,
    const float* __restrict__ bop, float* __restrict__ outp){
  __shared__ unsigned short As[128*64];
  __shared__ unsigned short Bs[128*64];
  oproj_side<32>(blockIdx.x, Cp, Wb + 7*262144, bop, outp, (char*)As, (char*)Bs);
}

// ---------------- fused QK^T + exp + rowsum + spill + ctx_d ----------------
__global__ __launch_bounds__(256) void k_attn_d(const unsigned short* __restrict__ Dm,
                                                const unsigned short* __restrict__ Pm,
                                                const unsigned short* __restrict__ Vpt,
                                                unsigned short* __restrict__ expS,
                                                float* __restrict__ rinv,
                                                unsigned short* __restrict__ Cd){
  __shared__ unsigned short Ds[128*128];
  __shared__ unsigned short Ps[128*128];
  __shared__ unsigned short Vs[64*128];
  const int id = blockIdx.x, xcd = id & 7, j = id >> 3;
  const int bh = xcd*32 + (j>>1), qt = j&1;
  const int b = bh>>3, h = bh&7;
  const int t = threadIdx.x, l = t&63, w = t>>6;
  char* DsB=(char*)Ds; char* PsB=(char*)Ps; char* VsB=(char*)Vs;
  const char* dsrc = (const char*)Dm + ((size_t)bh*256 + qt*128)*256;
  const char* psrc = (const char*)Pm + (size_t)bh*1024*256;
  const char* vsrc = (const char*)Vpt + (size_t)bh*64*2048;
  char* egbase = (char*)expS + ((size_t)bh*256 + qt*128)*2048;
  const int lofs = w*1024;

  for (int i=0;i<8;++i)
    gload16(dsrc + i*4096 + lofs + l*16, DsB + i*4096 + lofs);

  float rs[2][4] = {};
  f32x4 cacc[2][4] = {};
  for (int pt=0; pt<8; ++pt){
    __syncthreads();
    for (int i=0;i<8;++i)
      gload16(psrc + pt*32768 + i*4096 + lofs + l*16, PsB + i*4096 + lofs);
    for (int i=0;i<4;++i){
      const int ib = i*4096 + lofs + l*16;
      gload16(vsrc + (size_t)(ib>>8)*2048 + pt*256 + (ib&255), VsB + i*4096 + lofs);
    }
    __syncthreads();
    f32x4 acc[2][8] = {};
    for (int kt=0;kt<4;++kt){
      bf16x8 a[2];
      for (int fm=0;fm<2;++fm){
        const int row = w*32 + fm*16 + (l&15);
        const int byteo = (kt*64 + (l>>4)*16) ^ ((row&15)<<4);
        a[fm] = *(const bf16x8*)(DsB + row*256 + byteo);
      }
      __builtin_amdgcn_s_setprio(1);
      for (int fn=0;fn<8;++fn){
        const int row = fn*16 + (l&15);
        const int byteo = (kt*64 + (l>>4)*16) ^ ((row&15)<<4);
        bf16x8 bq = *(const bf16x8*)(PsB + row*256 + byteo);
        acc[0][fn] = mfma16(a[0], bq, acc[0][fn]);
        acc[1][fn] = mfma16(a[1], bq, acc[1][fn]);
      }
      __builtin_amdgcn_s_setprio(0);
    }
    __syncthreads();
    for (int fm=0;fm<2;++fm)
      for (int fn=0;fn<8;++fn)
        for (int r=0;r<4;++r){
          float e = __expf(acc[fm][fn][r]);
          rs[fm][r] += e;
          const int q = w*32 + fm*16 + (l>>4)*4 + r;
          const int p = fn*16 + (l&15);
          *(unsigned short*)(PsB + q*256 + ((p*2) ^ ((q&15)<<4))) = f2bf(e);
        }
    __syncthreads();
    for (int i=0;i<4;++i){
      const int idx = i*256 + t;
      const int row = idx>>3, colb = (idx&7)*32;
      int4 v0 = *(const int4*)(PsB + row*256 + colb);
      int4 v1 = *(const int4*)(PsB + row*256 + colb + 16);
      char* gp = egbase + (size_t)row*2048 + pt*256 + colb;
      *(int4*)gp = v0;
      *(int4*)(gp+16) = v1;
    }
    for (int kt=0;kt<4;++kt){
      bf16x8 pa[2], vb[4];
      for (int fm=0;fm<2;++fm){
        const int row = w*32 + fm*16 + (l&15);
        const int byteo = (kt*64 + (l>>4)*16) ^ ((row&15)<<4);
        pa[fm] = *(const bf16x8*)(PsB + row*256 + byteo);
      }
      for (int fn=0;fn<4;++fn){
        const int row = fn*16 + (l&15);
        const int byteo = (kt*64 + (l>>4)*16) ^ ((row&15)<<4);
        vb[fn] = *(const bf16x8*)(VsB + row*256 + byteo);
      }
      __builtin_amdgcn_s_setprio(1);
      for (int fm=0;fm<2;++fm)
        for (int fn=0;fn<4;++fn)
          cacc[fm][fn] = mfma16(pa[fm], vb[fn], cacc[fm][fn]);
      __builtin_amdgcn_s_setprio(0);
    }
  }
  for (int m=1;m<16;m<<=1)
    for (int fm=0;fm<2;++fm)
      for (int r=0;r<4;++r)
        rs[fm][r] += __shfl_xor(rs[fm][r], m, 64);
  float riv[2][4];
  for (int fm=0;fm<2;++fm)
    for (int r=0;r<4;++r)
      riv[fm][r] = 1.f/rs[fm][r];
  if ((l&15)==0){
    for (int fm=0;fm<2;++fm)
      for (int r=0;r<4;++r){
        const int row = w*32 + fm*16 + (l>>4)*4 + r;
        rinv[ (size_t)bh*256 + qt*128 + row ] = riv[fm][r];
      }
  }
  for (int fm=0;fm<2;++fm)
    for (int fn=0;fn<4;++fn)
      for (int r=0;r<4;++r){
        const int row = w*32 + fm*16 + (l>>4)*4 + r;
        const float v = cacc[fm][fn][r] * riv[fm][r];
        const int col = fn*16 + (l&15);
        Cd[ ((size_t)b*256 + qt*128 + row)*512 + h*64 + col ] = f2bf(v);
      }
}

// ---------------- ctx_p + fused normalized-attn write ----------------
__global__ __launch_bounds__(256) void k_ctxp_n(const unsigned short* __restrict__ expS,
                                                const unsigned short* __restrict__ Vdt,
                                                const float* __restrict__ rinv,
                                                unsigned short* __restrict__ Cp,
                                                float* __restrict__ attn){
  __shared__ unsigned short As[128*40];
  __shared__ unsigned short Bs[64*40];
  __shared__ float ri[256];
  const int id = blockIdx.x, xcd = id & 7, j = id >> 3;
  const int bh = xcd*32 + (j>>3), mt = j&7;
  const int b = bh>>3, h = bh&7;
  const int t = threadIdx.x, l = t&63, w = t>>6;
  ri[t] = rinv[ (size_t)bh*256 + t ];
  const char* ebase = (const char*)expS + (size_t)bh*256*2048;
  const unsigned short* vbase = Vdt + (size_t)bh*16384;
  f32x4 acc[2][4] = {};
  for (int kt=0; kt<8; ++kt){
    __syncthreads();
    for (int i=0;i<4;++i){
      const int idx = i*256 + t;
      const int ql = idx>>5, p4 = idx&31;
      const int qg = kt*32 + ql;
      ushort4 v = *(const ushort4*)(ebase + (size_t)qg*2048 + ((mt*256 + p4*8) ^ ((qg&15)<<4)));
      As[(p4*4+0)*40 + ql] = v.x;
      As[(p4*4+1)*40 + ql] = v.y;
      As[(p4*4+2)*40 + ql] = v.z;
      As[(p4*4+3)*40 + ql] = v.w;
      const float rv = ri[qg];
      f32x4 o;
      o[0] = bf2f(v.x) * rv; o[1] = bf2f(v.y) * rv;
      o[2] = bf2f(v.z) * rv; o[3] = bf2f(v.w) * rv;
      float* dst = attn + ((size_t)bh*256 + qg)*1024 + mt*128 + p4*4;
      __builtin_nontemporal_store(o, (f32x4*)dst);
    }
    for (int i=0;i<2;++i){
      const int idx = i*256 + t;
      const int row = idx>>3, c4 = idx&7;
      ushort4 vv = *(const ushort4*)(vbase + (size_t)row*256 + kt*32 + c4*4);
      const float* rp = &ri[kt*32 + c4*4];
      Bs[row*40 + c4*4+0] = f2bf(bf2f(vv.x) * rp[0]);
      Bs[row*40 + c4*4+1] = f2bf(bf2f(vv.y) * rp[1]);
      Bs[row*40 + c4*4+2] = f2bf(bf2f(vv.z) * rp[2]);
      Bs[row*40 + c4*4+3] = f2bf(bf2f(vv.w) * rp[3]);
    }
    __syncthreads();
    bf16x8 a[2], bb[4];
    for (int fm=0;fm<2;++fm)
      a[fm] = *(const bf16x8*)(As + (w*32 + fm*16 + (l&15))*40 + (l>>4)*8);
    for (int fn=0;fn<4;++fn)
      bb[fn] = *(const bf16x8*)(Bs + (fn*16 + (l&15))*40 + (l>>4)*8);
    for (int fm=0;fm<2;++fm)
      for (int fn=0;fn<4;++fn)
        acc[fm][fn] = mfma16(a[fm], bb[fn], acc[fm][fn]);
  }
  for (int fm=0;fm<2;++fm)
    for (int fn=0;fn<4;++fn)
      for (int r=0;r<4;++r){
        const int row = mt*128 + w*32 + fm*16 + (l>>4)*4 + r;
        const int col = fn*16 + (l&15);
        Cp[ ((size_t)b*1024 + row)*512 + h*64 + col ] = f2bf(acc[fm][fn][r]);
      }
}

extern "C" void kernel_launch(void* const* d_in, const int* in_sizes, int n_in,
                              void* d_out, int out_size, void* d_ws, size_t ws_size,
                              hipStream_t stream){
  const float* drug    = (const float*)d_in[0];
  const float* protein = (const float*)d_in[1];
  const float* Wqd=(const float*)d_in[2];  const float* bqd=(const float*)d_in[3];
  const float* Wkp=(const float*)d_in[4];  const float* bkp=(const float*)d_in[5];
  const float* Wvp=(const float*)d_in[6];  const float* bvp=(const float*)d_in[7];
  const float* Wqp=(const float*)d_in[8];  const float* bqp=(const float*)d_in[9];
  const float* Wkd=(const float*)d_in[10]; const float* bkd=(const float*)d_in[11];
  const float* Wvd=(const float*)d_in[12]; const float* bvd=(const float*)d_in[13];
  const float* alpha=(const float*)d_in[14];
  const float* Wod=(const float*)d_in[15]; const float* bod=(const float*)d_in[16];
  const float* Wop=(const float*)d_in[17]; const float* bop=(const float*)d_in[18];

  char* ws = (char*)d_ws;
  unsigned short* expS = (unsigned short*)(ws + 0);          // [bh][256][1024] bf16, p-swizzled
  unsigned short* Xd   = (unsigned short*)(ws + 0);          // dead after proj
  unsigned short* Xp   = (unsigned short*)(ws + 8388608);    // dead after proj
  unsigned short* Wb   = (unsigned short*)(ws + 134217728);  // 8 x 512x512 bf16
  unsigned short* Dm   = (unsigned short*)(ws + 138412032);  // dead after attn_d
  unsigned short* Pm   = (unsigned short*)(ws + 155189248);  // dead after attn_d
  unsigned short* Cp   = (unsigned short*)(ws + 155189248);  // overlay, written post-attn_d
  unsigned short* Vpt  = (unsigned short*)(ws + 222298112);  // [bh][64][1024] swizzled
  unsigned short* Vdt  = (unsigned short*)(ws + 255852544);  // [bh][64][256] linear
  float*          rinv = (float*)         (ws + 264241152);  // [bh*256]

  float* attn = (float*)d_out;
  float* outd = (float*)d_out + 67108864;
  float* outp = (float*)d_out + 71303168;
  // Cd in the attn region of d_out: written by attn_d, consumed by oproj_d,
  // then overwritten by ctxp_n's attn write. No ws overlap -> no cross-kernel race.
  unsigned short* Cd = (unsigned short*)d_out;

  CvtArgs ca;
  ca.drug = drug; ca.protein = protein;
  ca.w[0]=Wqd; ca.w[1]=Wkd; ca.w[2]=Wvd; ca.w[3]=Wkp; ca.w[4]=Wqp; ca.w[5]=Wvp; ca.w[6]=Wod; ca.w[7]=Wop;
  k_cvt_all<<<4096, 256, 0, stream>>>(ca, Xd, Xp, Wb);

  k_proj_all<<<3840, 256, 0, stream>>>(Xd, Xp, Wb, bqd, bkd, bvd, bkp, bqp, bvp,
                                       Dm, Pm, Vpt, Vdt, alpha);

  // fused QK + exp + spill + ctx_d (Cd -> d_out attn region)
  k_attn_d<<<512, 256, 0, stream>>>(Dm, Pm, Vpt, expS, rinv, Cd);

  // drug output projection consumes Cd
  k_oproj_d<<<256, 256, 0, stream>>>(Cd, Wb, bod, outd);

  // ctx_p + fused normalized f32 attn write (overwrites Cd region)
  k_ctxp_n<<<2048, 256, 0, stream>>>(expS, Vdt, rinv, Cp, attn);

  // protein output projection
  k_oproj_p<<<1024, 256, 0, stream>>>(Cp, Wb, bop, outp);
}